// Round 1
// baseline (1377.062 us; speedup 1.0000x reference)
//
#include <hip/hip_runtime.h>

#define NSP 32
#define BB  16
#define CC  64
#define HH  512
#define WW  512
#define HW  (HH * WW)

#define CBLK   16          // channels per block in accum kernel
#define CHUNK  8192        // pixels per block chunk
#define NCHUNK (HW / CHUNK)
#define BLOCK  256

#define CNT_CHUNK 16384

// ---------------------------------------------------------------------------
// Kernel 1: segmented sums. grid = (pixel chunks, channel groups, batch)
// Stage chunk indices once in LDS (packed u8), reuse across CBLK channels.
// ---------------------------------------------------------------------------
__global__ __launch_bounds__(BLOCK) void sp_accum(const float* __restrict__ feats,
                                                  const int*   __restrict__ spidx,
                                                  float*       __restrict__ sums /*[B][C][NSP]*/)
{
    __shared__ unsigned int s_idx[CHUNK / 4];        // 4 packed u8 indices per word
    __shared__ float s_bins[CBLK][NSP + 1];          // +1 pad -> banks spread

    const int tid   = threadIdx.x;
    const int chunk = blockIdx.x;
    const int cg    = blockIdx.y;
    const int b     = blockIdx.z;
    const int pix0  = chunk * CHUNK;

    for (int i = tid; i < CBLK * (NSP + 1); i += BLOCK)
        (&s_bins[0][0])[i] = 0.0f;

    // stage indices: CHUNK ints -> CHUNK bytes in LDS
    const int4* ip = (const int4*)(spidx + (size_t)b * HW + pix0);
    for (int i = tid; i < CHUNK / 4; i += BLOCK) {
        int4 v = ip[i];
        s_idx[i] = (unsigned)(v.x & 255)
                 | ((unsigned)(v.y & 255) << 8)
                 | ((unsigned)(v.z & 255) << 16)
                 | ((unsigned)(v.w & 255) << 24);
    }
    __syncthreads();

    for (int cl = 0; cl < CBLK; ++cl) {
        const int c = cg * CBLK + cl;
        const float4* fp = (const float4*)(feats + ((size_t)b * CC + c) * HW + pix0);
        for (int i = tid; i < CHUNK / 4; i += BLOCK) {
            float4 v  = fp[i];
            unsigned u = s_idx[i];
            atomicAdd(&s_bins[cl][ u        & 31], v.x);
            atomicAdd(&s_bins[cl][(u >> 8)  & 31], v.y);
            atomicAdd(&s_bins[cl][(u >> 16) & 31], v.z);
            atomicAdd(&s_bins[cl][(u >> 24) & 31], v.w);
        }
    }
    __syncthreads();

    // flush block partials: 512 bins -> global atomics (32 blocks contend per slot)
    for (int i = tid; i < CBLK * NSP; i += BLOCK) {
        int cl = i >> 5, sp = i & 31;
        atomicAdd(&sums[((size_t)b * CC + cg * CBLK + cl) * NSP + sp], s_bins[cl][sp]);
    }
}

// ---------------------------------------------------------------------------
// Kernel 2: per-(batch, superpixel) pixel counts
// ---------------------------------------------------------------------------
__global__ __launch_bounds__(BLOCK) void sp_count(const int* __restrict__ spidx,
                                                  float*     __restrict__ counts /*[B][NSP]*/)
{
    __shared__ int s_cnt[NSP];
    const int tid  = threadIdx.x;
    const int b    = blockIdx.y;
    const int pix0 = blockIdx.x * CNT_CHUNK;

    if (tid < NSP) s_cnt[tid] = 0;
    __syncthreads();

    const int4* ip = (const int4*)(spidx + (size_t)b * HW + pix0);
    for (int i = tid; i < CNT_CHUNK / 4; i += BLOCK) {
        int4 v = ip[i];
        atomicAdd(&s_cnt[v.x & 31], 1);
        atomicAdd(&s_cnt[v.y & 31], 1);
        atomicAdd(&s_cnt[v.z & 31], 1);
        atomicAdd(&s_cnt[v.w & 31], 1);
    }
    __syncthreads();

    if (tid < NSP) atomicAdd(&counts[b * NSP + tid], (float)s_cnt[tid]);
}

// ---------------------------------------------------------------------------
// Kernel 3: mean + pairwise similarity. One block per batch.
// out layout: sp [B][NSP][C] at 0, sim [B][NSP][NSP] at B*NSP*C
// ---------------------------------------------------------------------------
__global__ __launch_bounds__(BLOCK) void sp_finalize(const float* __restrict__ sums,
                                                     const float* __restrict__ counts,
                                                     float*       __restrict__ out)
{
    __shared__ float s_sp[NSP][CC + 1];   // pad -> conflict-free column reads
    const int b   = blockIdx.x;
    const int tid = threadIdx.x;

    for (int i = tid; i < NSP * CC; i += BLOCK) {
        int sp = i >> 6, c = i & 63;
        float cnt = counts[b * NSP + sp];
        float s   = sums[((size_t)b * CC + c) * NSP + sp];
        float v   = (cnt > 0.0f) ? (s / cnt) : 0.0f;
        s_sp[sp][c] = v;
        out[(size_t)b * NSP * CC + (size_t)sp * CC + c] = v;
    }
    __syncthreads();

    for (int p = tid; p < NSP * NSP; p += BLOCK) {
        int i = p >> 5, j = p & 31;
        float acc = 0.0f;
#pragma unroll
        for (int c = 0; c < CC; ++c) {
            float d = s_sp[i][c] - s_sp[j][c];
            acc = fmaf(d, d, acc);
        }
        out[(size_t)BB * NSP * CC + (size_t)b * NSP * NSP + p] = 1.0f - 0.5f * acc;
    }
}

// ---------------------------------------------------------------------------
extern "C" void kernel_launch(void* const* d_in, const int* in_sizes, int n_in,
                              void* d_out, int out_size, void* d_ws, size_t ws_size,
                              hipStream_t stream)
{
    const float* feats = (const float*)d_in[0];
    const int*   spidx = (const int*)d_in[1];
    float*       out   = (float*)d_out;

    float* sums   = (float*)d_ws;                       // B*C*NSP = 32768 floats
    float* counts = sums + (size_t)BB * CC * NSP;       // B*NSP   = 512 floats

    hipMemsetAsync(d_ws, 0, ((size_t)BB * CC * NSP + (size_t)BB * NSP) * sizeof(float), stream);

    dim3 g1(NCHUNK, CC / CBLK, BB);
    sp_accum<<<g1, BLOCK, 0, stream>>>(feats, spidx, sums);

    dim3 g2(HW / CNT_CHUNK, BB);
    sp_count<<<g2, BLOCK, 0, stream>>>(spidx, counts);

    sp_finalize<<<BB, BLOCK, 0, stream>>>(sums, counts, out);
}

// Round 2
// 224.550 us; speedup vs baseline: 6.1325x; 6.1325x over previous
//
#include <hip/hip_runtime.h>

#define NSP 32
#define BB  16
#define CC  64
#define HH  512
#define WW  512
#define HW  (HH * WW)

#define CHUNK  8192        // pixels per block (accum kernel)
#define BLOCK  256
#define NCHUNK (HW / CHUNK)

#define CNT_CHUNK 16384

// ---------------------------------------------------------------------------
// Kernel 1: segmented sums via per-thread privatized LDS bins (no LDS atomics).
// grid = (pixel chunks, batch). Each block sweeps all 64 channels in pairs;
// the two channels of a pair share one float2 RMW per pixel.
// ---------------------------------------------------------------------------
__global__ __launch_bounds__(BLOCK) void sp_accum(const float* __restrict__ feats,
                                                  const int*   __restrict__ spidx,
                                                  float*       __restrict__ sums /*[B][C][NSP]*/)
{
    __shared__ unsigned char s_idx[CHUNK];            // 8 KB, staged once
    __shared__ float2 s_priv[BLOCK][NSP + 1];         // 66 KB, +1 pad -> bank spread
    __shared__ float2 s_part[8][NSP];                 // 2 KB group partials

    const int tid  = threadIdx.x;
    const int b    = blockIdx.y;
    const int pix0 = blockIdx.x * CHUNK;

    // stage indices as bytes (read once, reused for all 32 channel-pairs)
    const int4* ip = (const int4*)(spidx + (size_t)b * HW + pix0);
    uchar4* sip = (uchar4*)s_idx;
    for (int i = tid; i < CHUNK / 4; i += BLOCK) {
        int4 v = ip[i];
        sip[i] = make_uchar4((unsigned char)(v.x & 31), (unsigned char)(v.y & 31),
                             (unsigned char)(v.z & 31), (unsigned char)(v.w & 31));
    }
#pragma unroll
    for (int sp = 0; sp < NSP; ++sp) s_priv[tid][sp] = make_float2(0.f, 0.f);
    __syncthreads();

    const int bin = tid & 31;
    const int grp = tid >> 5;        // 8 groups of 32 threads

    for (int cp = 0; cp < CC; cp += 2) {
        const float4* f0 = (const float4*)(feats + ((size_t)b * CC + cp)     * HW + pix0);
        const float4* f1 = (const float4*)(feats + ((size_t)b * CC + cp + 1) * HW + pix0);
        float2* row = s_priv[tid];

#pragma unroll
        for (int k = 0; k < CHUNK / 4 / BLOCK; ++k) {    // 8 iterations
            const int i = k * BLOCK + tid;               // coalesced float4 loads
            float4 a = f0[i];
            float4 c = f1[i];
            uchar4 u = sip[i];
            float2 t;
            t = row[u.x]; t.x += a.x; t.y += c.x; row[u.x] = t;
            t = row[u.y]; t.x += a.y; t.y += c.y; row[u.y] = t;
            t = row[u.z]; t.x += a.z; t.y += c.z; row[u.z] = t;
            t = row[u.w]; t.x += a.w; t.y += c.w; row[u.w] = t;
        }
        __syncthreads();

        // fold 256 copies: 8 threads per bin, 32 copies each (copy = grp + 8m)
        float2 acc = make_float2(0.f, 0.f);
#pragma unroll
        for (int m = 0; m < BLOCK / 8; ++m) {
            float2 v = s_priv[grp + m * 8][bin];
            acc.x += v.x; acc.y += v.y;
        }
        s_part[grp][bin] = acc;
        __syncthreads();

        // re-zero own row for the next pass (after all fold reads completed)
        if (cp + 2 < CC) {
#pragma unroll
            for (int sp = 0; sp < NSP; ++sp) s_priv[tid][sp] = make_float2(0.f, 0.f);
        }
        if (tid < NSP) {
            float2 r = s_part[0][tid];
#pragma unroll
            for (int g2 = 1; g2 < 8; ++g2) { r.x += s_part[g2][tid].x; r.y += s_part[g2][tid].y; }
            atomicAdd(&sums[((size_t)b * CC + cp)     * NSP + tid], r.x);
            atomicAdd(&sums[((size_t)b * CC + cp + 1) * NSP + tid], r.y);
        }
        __syncthreads();   // s_part / s_priv safe before next pass
    }
}

// ---------------------------------------------------------------------------
// Kernel 2: pixel counts, also privatized (no LDS atomics in the hot loop)
// ---------------------------------------------------------------------------
__global__ __launch_bounds__(BLOCK) void sp_count(const int* __restrict__ spidx,
                                                  float*     __restrict__ counts /*[B][NSP]*/)
{
    __shared__ int s_cnt[BLOCK][NSP + 1];   // 33.8 KB
    __shared__ int s_tot[NSP];
    const int tid  = threadIdx.x;
    const int b    = blockIdx.y;
    const int pix0 = blockIdx.x * CNT_CHUNK;

#pragma unroll
    for (int sp = 0; sp < NSP; ++sp) s_cnt[tid][sp] = 0;
    if (tid < NSP) s_tot[tid] = 0;
    __syncthreads();

    const int4* ip = (const int4*)(spidx + (size_t)b * HW + pix0);
    int* row = s_cnt[tid];
    for (int i = tid; i < CNT_CHUNK / 4; i += BLOCK) {
        int4 v = ip[i];
        row[v.x & 31]++;
        row[v.y & 31]++;
        row[v.z & 31]++;
        row[v.w & 31]++;
    }
    __syncthreads();

    const int bin = tid & 31, grp = tid >> 5;
    int acc = 0;
#pragma unroll
    for (int m = 0; m < BLOCK / 8; ++m) acc += s_cnt[grp + m * 8][bin];
    atomicAdd(&s_tot[bin], acc);
    __syncthreads();

    if (tid < NSP) atomicAdd(&counts[b * NSP + tid], (float)s_tot[tid]);
}

// ---------------------------------------------------------------------------
// Kernel 3: mean + pairwise similarity. One block per batch.
// out layout: sp [B][NSP][C] at 0, sim [B][NSP][NSP] at B*NSP*C
// ---------------------------------------------------------------------------
__global__ __launch_bounds__(BLOCK) void sp_finalize(const float* __restrict__ sums,
                                                     const float* __restrict__ counts,
                                                     float*       __restrict__ out)
{
    __shared__ float s_sp[NSP][CC + 1];
    const int b   = blockIdx.x;
    const int tid = threadIdx.x;

    for (int i = tid; i < NSP * CC; i += BLOCK) {
        int sp = i >> 6, c = i & 63;
        float cnt = counts[b * NSP + sp];
        float s   = sums[((size_t)b * CC + c) * NSP + sp];
        float v   = (cnt > 0.0f) ? (s / cnt) : 0.0f;
        s_sp[sp][c] = v;
        out[(size_t)b * NSP * CC + (size_t)sp * CC + c] = v;
    }
    __syncthreads();

    for (int p = tid; p < NSP * NSP; p += BLOCK) {
        int i = p >> 5, j = p & 31;
        float acc = 0.0f;
#pragma unroll
        for (int c = 0; c < CC; ++c) {
            float d = s_sp[i][c] - s_sp[j][c];
            acc = fmaf(d, d, acc);
        }
        out[(size_t)BB * NSP * CC + (size_t)b * NSP * NSP + p] = 1.0f - 0.5f * acc;
    }
}

// ---------------------------------------------------------------------------
extern "C" void kernel_launch(void* const* d_in, const int* in_sizes, int n_in,
                              void* d_out, int out_size, void* d_ws, size_t ws_size,
                              hipStream_t stream)
{
    const float* feats = (const float*)d_in[0];
    const int*   spidx = (const int*)d_in[1];
    float*       out   = (float*)d_out;

    float* sums   = (float*)d_ws;                       // B*C*NSP = 65536 floats
    float* counts = sums + (size_t)BB * CC * NSP;       // B*NSP   = 512 floats

    hipMemsetAsync(d_ws, 0, ((size_t)BB * CC * NSP + (size_t)BB * NSP) * sizeof(float), stream);

    dim3 g1(NCHUNK, BB);
    sp_accum<<<g1, BLOCK, 0, stream>>>(feats, spidx, sums);

    dim3 g2(HW / CNT_CHUNK, BB);
    sp_count<<<g2, BLOCK, 0, stream>>>(spidx, counts);

    sp_finalize<<<BB, BLOCK, 0, stream>>>(sums, counts, out);
}

// Round 3
// 213.172 us; speedup vs baseline: 6.4599x; 1.0534x over previous
//
#include <hip/hip_runtime.h>

#define NSP 32
#define BB  16
#define CC  64
#define HW  (512 * 512)

#define BLOCK  256
#define CHUNK  8192
#define NCHUNK (HW / CHUNK)      // 32
#define KIT    (CHUNK / 4 / BLOCK)  // 8 float4-iters per thread per pass

// Barrier that does NOT drain vmcnt: all cross-thread deps here are LDS-only,
// so prefetched global loads may stay in flight across the fold phase.
#define BAR() asm volatile("s_waitcnt lgkmcnt(0)\n\ts_barrier" ::: "memory")

// ---------------------------------------------------------------------------
// Segmented sums + counts. Per-thread privatized LDS bins (no atomics in the
// hot loop). Each block: one 8192-pixel chunk, sweeps 64 channels in pairs.
// Next pass's feature data is fully prefetched into registers before the
// fold barrier, so HBM never idles during fold/rezero.
// ---------------------------------------------------------------------------
__global__ __launch_bounds__(BLOCK) void sp_accum(const float* __restrict__ feats,
                                                  const int*   __restrict__ spidx,
                                                  float*       __restrict__ sums  /*[B][C][NSP]*/,
                                                  float*       __restrict__ counts/*[B][NSP]*/)
{
    __shared__ uchar4 s_idx[CHUNK / 4];               // 8 KB
    __shared__ float2 s_priv[BLOCK][NSP + 1];         // 66 KB, pad -> bank spread
    __shared__ float2 s_part[8][NSP];                 // 2 KB

    const int tid  = threadIdx.x;
    const int b    = blockIdx.y;
    const int pix0 = blockIdx.x * CHUNK;
    const int bin  = tid & 31;
    const int grp  = tid >> 5;

    // stage indices as bytes (read once from HBM, reused for all passes)
    const int4* ip = (const int4*)(spidx + (size_t)b * HW + pix0);
#pragma unroll
    for (int n = 0; n < (CHUNK / 4) / BLOCK; ++n) {
        const int i = n * BLOCK + tid;
        int4 v = ip[i];
        s_idx[i] = make_uchar4((unsigned char)(v.x & 31), (unsigned char)(v.y & 31),
                               (unsigned char)(v.z & 31), (unsigned char)(v.w & 31));
    }
#pragma unroll
    for (int sp = 0; sp < NSP; ++sp) s_priv[tid][sp] = make_float2(0.f, 0.f);

    // prologue: prefetch pass 0 (channels 0,1) fully — in flight during count phase
    const float* fb = feats + (size_t)b * CC * HW + pix0;
    float4 pre[KIT][2];
#pragma unroll
    for (int k = 0; k < KIT; ++k) {
        pre[k][0] = ((const float4*)fb)[k * BLOCK + tid];
        pre[k][1] = ((const float4*)(fb + (size_t)HW))[k * BLOCK + tid];
    }

    BAR();

    // ---- fused pixel counts (uses .x plane of the private bins) ----
    {
        float* rowf = (float*)&s_priv[tid][0];
#pragma unroll
        for (int k = 0; k < KIT; ++k) {
            uchar4 u = s_idx[k * BLOCK + tid];
            rowf[u.x * 2] += 1.f;
            rowf[u.y * 2] += 1.f;
            rowf[u.z * 2] += 1.f;
            rowf[u.w * 2] += 1.f;
        }
    }
    BAR();
    {
        float a = 0.f;
#pragma unroll
        for (int m = 0; m < BLOCK / 8; ++m) a += s_priv[grp + m * 8][bin].x;
        s_part[grp][bin].x = a;
    }
    BAR();
    if (tid < NSP) {
        float r = 0.f;
#pragma unroll
        for (int g = 0; g < 8; ++g) r += s_part[g][tid].x;
        atomicAdd(&counts[b * NSP + tid], r);
    }
#pragma unroll
    for (int sp = 0; sp < NSP; ++sp) s_priv[tid][sp] = make_float2(0.f, 0.f);
    BAR();

    // ---- main channel-pair passes ----
    float2* row = s_priv[tid];
    for (int cp = 0; cp < CC / 2; ++cp) {
        // A: accumulate this pass from prefetched registers
#pragma unroll
        for (int k = 0; k < KIT; ++k) {
            uchar4 u = s_idx[k * BLOCK + tid];
            float4 a = pre[k][0], c = pre[k][1];
            float2 t;
            t = row[u.x]; t.x += a.x; t.y += c.x; row[u.x] = t;
            t = row[u.y]; t.x += a.y; t.y += c.y; row[u.y] = t;
            t = row[u.z]; t.x += a.z; t.y += c.z; row[u.z] = t;
            t = row[u.w]; t.x += a.w; t.y += c.w; row[u.w] = t;
        }
        // B: issue next pass's loads — they stay in flight across the fold
        if (cp + 1 < CC / 2) {
            const float* g0 = fb + (size_t)(2 * cp + 2) * HW;
#pragma unroll
            for (int k = 0; k < KIT; ++k) {
                pre[k][0] = ((const float4*)g0)[k * BLOCK + tid];
                pre[k][1] = ((const float4*)(g0 + (size_t)HW))[k * BLOCK + tid];
            }
        }
        BAR();
        // fold 256 private copies: 8 threads per bin, 32 copies each
        {
            float2 acc = make_float2(0.f, 0.f);
#pragma unroll
            for (int m = 0; m < BLOCK / 8; ++m) {
                float2 v = s_priv[grp + m * 8][bin];
                acc.x += v.x; acc.y += v.y;
            }
            s_part[grp][bin] = acc;
        }
        BAR();
        if (cp + 1 < CC / 2) {
#pragma unroll
            for (int sp = 0; sp < NSP; ++sp) row[sp] = make_float2(0.f, 0.f);
        }
        if (tid < NSP) {
            float2 r = s_part[0][tid];
#pragma unroll
            for (int g = 1; g < 8; ++g) { r.x += s_part[g][tid].x; r.y += s_part[g][tid].y; }
            atomicAdd(&sums[((size_t)b * CC + 2 * cp)     * NSP + tid], r.x);
            atomicAdd(&sums[((size_t)b * CC + 2 * cp + 1) * NSP + tid], r.y);
        }
        BAR();
    }
}

// ---------------------------------------------------------------------------
// Mean + pairwise similarity. One block per batch.
// out layout: sp [B][NSP][C] at 0, sim [B][NSP][NSP] at B*NSP*C
// ---------------------------------------------------------------------------
__global__ __launch_bounds__(BLOCK) void sp_finalize(const float* __restrict__ sums,
                                                     const float* __restrict__ counts,
                                                     float*       __restrict__ out)
{
    __shared__ float s_sp[NSP][CC + 1];
    const int b   = blockIdx.x;
    const int tid = threadIdx.x;

    for (int i = tid; i < NSP * CC; i += BLOCK) {
        int sp = i >> 6, c = i & 63;
        float cnt = counts[b * NSP + sp];
        float s   = sums[((size_t)b * CC + c) * NSP + sp];
        float v   = (cnt > 0.0f) ? (s / cnt) : 0.0f;
        s_sp[sp][c] = v;
        out[(size_t)b * NSP * CC + (size_t)sp * CC + c] = v;
    }
    __syncthreads();

    for (int p = tid; p < NSP * NSP; p += BLOCK) {
        int i = p >> 5, j = p & 31;
        float acc = 0.0f;
#pragma unroll
        for (int c = 0; c < CC; ++c) {
            float d = s_sp[i][c] - s_sp[j][c];
            acc = fmaf(d, d, acc);
        }
        out[(size_t)BB * NSP * CC + (size_t)b * NSP * NSP + p] = 1.0f - 0.5f * acc;
    }
}

// ---------------------------------------------------------------------------
extern "C" void kernel_launch(void* const* d_in, const int* in_sizes, int n_in,
                              void* d_out, int out_size, void* d_ws, size_t ws_size,
                              hipStream_t stream)
{
    const float* feats = (const float*)d_in[0];
    const int*   spidx = (const int*)d_in[1];
    float*       out   = (float*)d_out;

    float* sums   = (float*)d_ws;                     // B*C*NSP = 32768 floats
    float* counts = sums + (size_t)BB * CC * NSP;     // B*NSP   = 512 floats

    hipMemsetAsync(d_ws, 0, ((size_t)BB * CC * NSP + (size_t)BB * NSP) * sizeof(float), stream);

    dim3 g1(NCHUNK, BB);
    sp_accum<<<g1, BLOCK, 0, stream>>>(feats, spidx, sums, counts);

    sp_finalize<<<BB, BLOCK, 0, stream>>>(sums, counts, out);
}